// Round 12
// baseline (388.864 us; speedup 1.0000x reference)
//
#include <hip/hip_runtime.h>
#include <math.h>

#define CC 96
#define BB 512
#define TT 512
#define NBLK 256   // 2 chains per block

// ---------------------------------------------------------------------------
// Kernel 0: column max of transitions and E[i][j] = exp(T[i][j]-maxT[j])
// ---------------------------------------------------------------------------
__global__ __launch_bounds__(128) void crf_prep(const float* __restrict__ trans,
                                                float* __restrict__ E,
                                                float* __restrict__ maxT) {
    int j = threadIdx.x;
    if (j < CC) {
        float m = -INFINITY;
        for (int i = 0; i < CC; ++i) m = fmaxf(m, trans[i * CC + j]);
        maxT[j] = m;
        for (int i = 0; i < CC; ++i) E[i * CC + j] = __expf(trans[i * CC + j] - m);
    }
}

// ---------------------------------------------------------------------------
// Kernel 0b: pack mask rows into bit-words (no per-step SMEM loads).
// ---------------------------------------------------------------------------
__global__ __launch_bounds__(64) void pack_mask(const int* __restrict__ mask,
                                                unsigned* __restrict__ mbits) {
    const int b = blockIdx.x;
    const int w = threadIdx.x;
    if (w < 16) {
        unsigned bits = 0u;
        for (int k = 0; k < 32; ++k)
            bits |= (mask[b * TT + w * 32 + k] ? 1u : 0u) << k;
        mbits[b * 16 + w] = bits;
    }
}

// ---------------------------------------------------------------------------
// Kernel 1: forward recurrence, linear space, i-SPLIT (r11 skeleton) with
// TWO chains per block sharing the E registers. r11 result: VGPR=80, step
// latency 1133cy of which ~800 is the serial LDS/sync chain — with 1 wave
// per SIMD nothing hides it. Chain B's fma+reads issue inside chain A's
// latency windows (ILP within the wave). One lgkm+barrier per step serves
// both chains. Renorm staggered: A at t%8==0, B at t%8==4.
// ---------------------------------------------------------------------------
#define PKFMA_LO(A_, S_, E_) \
    asm("v_pk_fma_f32 %0, %1, %2, %0 op_sel:[0,0,0] op_sel_hi:[0,1,1]" \
        : "+v"(A_) : "v"(S_), "v"(E_))
#define PKFMA_HI(A_, S_, E_) \
    asm("v_pk_fma_f32 %0, %1, %2, %0 op_sel:[1,0,0] op_sel_hi:[1,1,1]" \
        : "+v"(A_) : "v"(S_), "v"(E_))

// partial for chain C_: own-half p reads (broadcast) + 48 pk_fma + pex write
#define PREP(C_, PR_)                                                         \
    float2 C_##m;                                                             \
    {                                                                         \
        float2 a0={0.f,0.f}, a1={0.f,0.f}, a2={0.f,0.f}, a3={0.f,0.f};        \
        _Pragma("unroll")                                                     \
        for (int i_ = 0; i_ < 48; i_ += 4) {                                  \
            const float2 p0_ = *(const float2*)&pb##C_[w][PR_][i_];           \
            const float2 p1_ = *(const float2*)&pb##C_[w][PR_][i_ + 2];       \
            PKFMA_LO(a0, p0_, ep2[i_]);                                       \
            PKFMA_HI(a1, p0_, ep2[i_ + 1]);                                   \
            PKFMA_LO(a2, p1_, ep2[i_ + 2]);                                   \
            PKFMA_HI(a3, p1_, ep2[i_ + 3]);                                   \
        }                                                                     \
        C_##m.x = (a0.x + a1.x) + (a2.x + a3.x);                              \
        C_##m.y = (a0.y + a1.y) + (a2.y + a3.y);                              \
    }                                                                         \
    if (act) *(float2*)&pex##C_[w][PR_][2 * l] = C_##m;

// finalize for chain C_: read other wave's partial, scale, renorm, p write
#define POSTP(C_, PR_, BIT_, REN_, SCX_, SCY_)                                \
    {                                                                         \
        const float2 o_ = *(const float2*)&pex##C_[1 - w][PR_][2 * lc];       \
        const float qx_ = C_##m.x + o_.x;                                     \
        const float qy_ = C_##m.y + o_.y;                                     \
        if (BIT_) { px##C_ = qx_ * (SCX_); py##C_ = qy_ * (SCY_); }           \
        if (REN_) {                                                           \
            float r_ = px##C_ + py##C_;                                       \
            _Pragma("unroll")                                                 \
            for (int o2_ = 32; o2_; o2_ >>= 1) r_ += __shfl_xor(r_, o2_);     \
            const float inv_ = 1.0f / r_;                                     \
            px##C_ *= inv_; py##C_ *= inv_;                                   \
            S##C_ += (double)__logf(r_);                                      \
        }                                                                     \
        if (l >= wlo && l < whi)                                              \
            *(float2*)&pb##C_[w][(PR_) ^ 1][2 * l - 48 * w] =                 \
                make_float2(px##C_, py##C_);                                  \
    }

#define STEP2(PFA_, PFB_, K_, BITA_, BITB_, RENA_, RENB_) do {                \
    const int sl_ = (K_) & 3;                                                 \
    const int pr_ = (K_) & 1;                                                 \
    const float2 ceA_ = esA[sl_]; esA[sl_] = *(const float2*)(PFA_);          \
    const float2 ceB_ = esB[sl_]; esB[sl_] = *(const float2*)(PFB_);          \
    const float scxA_ = __expf(mTx + ceA_.x);                                 \
    const float scyA_ = __expf(mTy + ceA_.y);                                 \
    const float scxB_ = __expf(mTx + ceB_.x);                                 \
    const float scyB_ = __expf(mTy + ceB_.y);                                 \
    PREP(A, pr_)                                                              \
    PREP(B, pr_)                                                              \
    asm volatile("s_waitcnt lgkmcnt(0)" ::: "memory");                        \
    __builtin_amdgcn_s_barrier();                                             \
    POSTP(A, pr_, BITA_, RENA_, scxA_, scyA_)                                 \
    POSTP(B, pr_, BITB_, RENB_, scxB_, scyB_)                                 \
} while (0)

__global__ __launch_bounds__(128, 1)
void crf_forward(const float* __restrict__ emissions,
                 const unsigned* __restrict__ mbits,
                 const float* __restrict__ start_t,
                 const float* __restrict__ end_t,
                 const float* __restrict__ E,
                 const float* __restrict__ maxT,
                 float* __restrict__ log_den) {
    const int bA = blockIdx.x;
    const int bB = blockIdx.x + NBLK;
    const int w = threadIdx.x >> 6;       // wave 0/1: owns i-rows 48w..48w+47
    const int l = threadIdx.x & 63;       // lane: owns output pair (2l, 2l+1)
    const bool act = (l < 48);
    const int lc = act ? l : 47;
    const int s0 = 2 * lc;
    const int wlo = 24 * w, whi = 24 * w + 24;

    __shared__ __align__(16) float pbA[2][2][48], pbB[2][2][48];   // [wave][parity][i-local]
    __shared__ __align__(16) float pexA[2][2][CC], pexB[2][2][CC]; // partial exchange

    // E rows (48w + i) at columns (s0, s0+1) -> 48 float2 = 96 VGPRs, SHARED by both chains
    float2 ep2[48];
#pragma unroll
    for (int i = 0; i < 48; ++i)
        ep2[i] = *(const float2*)(E + (size_t)(48 * w + i) * CC + s0);

    const float* epA = emissions + (size_t)bA * TT * CC + s0;
    const float* epB = emissions + (size_t)bB * TT * CC + s0;
    const float mTx = act ? maxT[s0]     : -INFINITY;
    const float mTy = act ? maxT[s0 + 1] : -INFINITY;

    // init t=0 (replicated in both waves)
    float pxA = 0.f, pyA = 0.f, pxB = 0.f, pyB = 0.f;
    {
        const float2 e0 = *(const float2*)epA;
        if (act) { pxA = __expf(start_t[s0] + e0.x); pyA = __expf(start_t[s0 + 1] + e0.y); }
    }
    {
        const float2 e0 = *(const float2*)epB;
        if (act) { pxB = __expf(start_t[s0] + e0.x); pyB = __expf(start_t[s0 + 1] + e0.y); }
    }
    double SA = 0.0, SB = 0.0;
    if (l >= wlo && l < whi) {
        *(float2*)&pbA[w][1][2 * l - 48 * w] = make_float2(pxA, pyA);
        *(float2*)&pbB[w][1][2 * l - 48 * w] = make_float2(pxB, pyB);
    }

    // emission prefetch slots: es[t&3] holds emission(t), t=1..4
    float2 esA[4], esB[4];
#pragma unroll
    for (int s = 1; s <= 4; ++s) {
        esA[s & 3] = *(const float2*)(epA + (size_t)s * CC);
        esB[s & 3] = *(const float2*)(epB + (size_t)s * CC);
    }
    const float* pfA = epA + (size_t)5 * CC;
    const float* pfB = epB + (size_t)5 * CC;

    // head: t = 1..7 (B renorms at t=4)
    const unsigned wbA0 = mbits[bA * 16];
    const unsigned wbB0 = mbits[bB * 16];
#pragma unroll
    for (int k = 1; k < 8; ++k) {
        STEP2(pfA, pfB, k, (wbA0 >> k) & 1u, (wbB0 >> k) & 1u, 0, k == 4);
        pfA += CC; pfB += CC;
    }
    // main: sb = 1..62 (t = 8*sb + k); A renorm at k==0, B at k==4
    unsigned swA = wbA0 >> 8, swB = wbB0 >> 8;
    for (int sb = 1; sb < 63; ++sb) {
        const int sbn = sb + 1;
        const unsigned snA = mbits[bA * 16 + (sbn >> 2)] >> ((sbn & 3) * 8);
        const unsigned snB = mbits[bB * 16 + (sbn >> 2)] >> ((sbn & 3) * 8);
#pragma unroll
        for (int k = 0; k < 8; ++k) {
            STEP2(pfA, pfB, k, (swA >> k) & 1u, (swB >> k) & 1u, k == 0, k == 4);
            pfA += CC; pfB += CC;
        }
        swA = snA; swB = snB;
    }
    // tail: t = 504..511, prefetch clamped to t=511
#pragma unroll
    for (int k = 0; k < 8; ++k) {
        const int t_ = 504 + k;
        const int tn_ = (t_ + 4 <= TT - 1) ? (t_ + 4) : (TT - 1);
        STEP2(epA + (size_t)tn_ * CC, epB + (size_t)tn_ * CC, k,
              (swA >> k) & 1u, (swB >> k) & 1u, k == 0, k == 4);
    }

    // final: log_den = S + log(sum_j p[j] * exp(end[j]))
    const float eex = act ? __expf(end_t[s0])     : 0.f;
    const float eey = act ? __expf(end_t[s0 + 1]) : 0.f;
    float frA = pxA * eex + pyA * eey;
    float frB = pxB * eex + pyB * eey;
#pragma unroll
    for (int off = 32; off; off >>= 1) {
        frA += __shfl_xor(frA, off);
        frB += __shfl_xor(frB, off);
    }
    if (threadIdx.x == 0) {
        log_den[bA] = (float)(SA + (double)__logf(frA));
        log_den[bB] = (float)(SB + (double)__logf(frB));
    }
}

// ---------------------------------------------------------------------------
// Kernel 2: joint likelihood (numerator) — one block per batch.
// ---------------------------------------------------------------------------
__global__ __launch_bounds__(256) void crf_joint(const float* __restrict__ emissions,
                                                 const int* __restrict__ tags,
                                                 const int* __restrict__ mask,
                                                 const float* __restrict__ trans,
                                                 const float* __restrict__ start_t,
                                                 const float* __restrict__ end_t,
                                                 float* __restrict__ log_num) {
    const int b = blockIdx.x;
    const int tid = threadIdx.x;
    float s = 0.f;
    int mcount = 0;
    for (int t = tid; t < TT; t += 256) {
        int tg = tags[b * TT + t];
        float em = emissions[((size_t)b * TT + t) * CC + tg];
        int mk = mask[b * TT + t];
        mcount += mk;
        if (t == 0) {
            s += start_t[tg] + em;  // t=0 term unmasked in reference
        } else {
            int tp = tags[b * TT + t - 1];
            s += mk ? (trans[tp * CC + tg] + em) : 0.f;
        }
    }
    __shared__ float sred[4];
    __shared__ int mred[4];
#pragma unroll
    for (int off = 32; off; off >>= 1) {
        s += __shfl_xor(s, off);
        mcount += __shfl_xor(mcount, off);
    }
    if ((tid & 63) == 0) { sred[tid >> 6] = s; mred[tid >> 6] = mcount; }
    __syncthreads();
    if (tid == 0) {
        float tot = (sred[0] + sred[1]) + (sred[2] + sred[3]);
        int mt = (mred[0] + mred[1]) + (mred[2] + mred[3]);
        int last_tag = tags[b * TT + (mt - 1)];
        log_num[b] = tot + end_t[last_tag];
    }
}

// ---------------------------------------------------------------------------
// Kernel 3: final mean(log_den - log_num)
// ---------------------------------------------------------------------------
__global__ __launch_bounds__(512) void crf_final(const float* __restrict__ log_den,
                                                 const float* __restrict__ log_num,
                                                 float* __restrict__ out) {
    const int tid = threadIdx.x;
    float d = log_den[tid] - log_num[tid];
#pragma unroll
    for (int off = 32; off; off >>= 1) d += __shfl_xor(d, off);
    __shared__ float sred[8];
    if ((tid & 63) == 0) sred[tid >> 6] = d;
    __syncthreads();
    if (tid == 0) {
        float tot = 0.f;
        for (int w = 0; w < 8; ++w) tot += sred[w];
        out[0] = tot / (float)BB;
    }
}

extern "C" void kernel_launch(void* const* d_in, const int* in_sizes, int n_in,
                              void* d_out, int out_size, void* d_ws, size_t ws_size,
                              hipStream_t stream) {
    const float* emissions = (const float*)d_in[0];
    const int*   tags      = (const int*)d_in[1];
    const int*   mask      = (const int*)d_in[2];
    const float* trans     = (const float*)d_in[3];
    const float* start_t   = (const float*)d_in[4];
    const float* end_t     = (const float*)d_in[5];
    float* out = (float*)d_out;

    float*    ws      = (float*)d_ws;
    float*    E       = ws;               // 9216 floats
    float*    maxT    = ws + 9216;        // 96
    float*    log_den = ws + 9312;        // 512
    float*    log_num = ws + 9824;        // 512
    unsigned* mbits   = (unsigned*)(ws + 10336);  // 512*16 u32

    crf_prep<<<1, 128, 0, stream>>>(trans, E, maxT);
    pack_mask<<<BB, 64, 0, stream>>>(mask, mbits);
    crf_forward<<<NBLK, 128, 0, stream>>>(emissions, mbits, start_t, end_t, E, maxT, log_den);
    crf_joint<<<BB, 256, 0, stream>>>(emissions, tags, mask, trans, start_t, end_t, log_num);
    crf_final<<<1, 512, 0, stream>>>(log_den, log_num, out);
}

// Round 14
// 208.215 us; speedup vs baseline: 1.8676x; 1.8676x over previous
//
#include <hip/hip_runtime.h>
#include <math.h>

#define CC 96
#define BB 512
#define TT 512

// ---------------------------------------------------------------------------
// Kernel 0: column max of transitions and E[i][j] = exp(T[i][j]-maxT[j])
// ---------------------------------------------------------------------------
__global__ __launch_bounds__(128) void crf_prep(const float* __restrict__ trans,
                                                float* __restrict__ E,
                                                float* __restrict__ maxT) {
    int j = threadIdx.x;
    if (j < CC) {
        float m = -INFINITY;
        for (int i = 0; i < CC; ++i) m = fmaxf(m, trans[i * CC + j]);
        maxT[j] = m;
        for (int i = 0; i < CC; ++i) E[i * CC + j] = __expf(trans[i * CC + j] - m);
    }
}

// ---------------------------------------------------------------------------
// Kernel 0b: pack mask rows into bit-words (no per-step SMEM loads).
// ---------------------------------------------------------------------------
__global__ __launch_bounds__(64) void pack_mask(const int* __restrict__ mask,
                                                unsigned* __restrict__ mbits) {
    const int b = blockIdx.x;
    const int w = threadIdx.x;
    if (w < 16) {
        unsigned bits = 0u;
        for (int k = 0; k < 32; ++k)
            bits |= (mask[b * TT + w * 32 + k] ? 1u : 0u) << k;
        mbits[b * 16 + w] = bits;
    }
}

// ---------------------------------------------------------------------------
// Kernel 1: forward recurrence, linear space, FOUR-way i-split, one chain per
// block, 512 blocks x 4 waves = 2048 waves = 2 waves/SIMD.
// r12 lesson: intra-wave dual-chain ILP gets serialized by the compiler
// (VALUBusy dropped 26->16%); latency hiding must come from hardware wave
// scheduling. r11 had exactly 1 wave/SIMD -> its ~800cy/step LDS latency was
// unfillable. Here each chain uses 4 small waves (24 E-rows = 48 VGPRs each),
// and each SIMD hosts waves from 2 DIFFERENT chains: when one stalls on the
// pex round-trip, the other issues.
// Per wave per step: 12 broadcast ds_read_b64 (own p-quarter) + 24 pk_fma
// (op_sel scalar broadcast) + pex write + lgkmcnt(0) + s_barrier + 4 pex
// reads + 3 adds + scale + own-quarter pb write (wave-ordered, no barrier).
// Renorm every 8 steps via shfl (replicated in all 4 waves).
// ---------------------------------------------------------------------------
#define PKFMA_LO(A_, S_, E_) \
    asm("v_pk_fma_f32 %0, %1, %2, %0 op_sel:[0,0,0] op_sel_hi:[0,1,1]" \
        : "+v"(A_) : "v"(S_), "v"(E_))
#define PKFMA_HI(A_, S_, E_) \
    asm("v_pk_fma_f32 %0, %1, %2, %0 op_sel:[1,0,0] op_sel_hi:[1,1,1]" \
        : "+v"(A_) : "v"(S_), "v"(E_))

#define STEP(PF_, K_, BIT_, REN_) do {                                        \
    const int sl_ = (K_) & 3;                                                 \
    const int pr_ = (K_) & 1;                                                 \
    const float2 ce_ = es[sl_];                                               \
    es[sl_] = *(const float2*)(PF_);                                          \
    const float scx_ = __expf(mTx + ce_.x);                                   \
    const float scy_ = __expf(mTy + ce_.y);                                   \
    float2 a0={0.f,0.f}, a1={0.f,0.f}, a2={0.f,0.f}, a3={0.f,0.f};            \
    _Pragma("unroll")                                                         \
    for (int i_ = 0; i_ < 24; i_ += 4) {                                      \
        const float2 p0_ = *(const float2*)&pb[w][pr_][i_];                   \
        const float2 p1_ = *(const float2*)&pb[w][pr_][i_ + 2];               \
        PKFMA_LO(a0, p0_, ep2[i_]);                                           \
        PKFMA_HI(a1, p0_, ep2[i_ + 1]);                                       \
        PKFMA_LO(a2, p1_, ep2[i_ + 2]);                                       \
        PKFMA_HI(a3, p1_, ep2[i_ + 3]);                                       \
    }                                                                         \
    float2 mine_;                                                             \
    mine_.x = (a0.x + a1.x) + (a2.x + a3.x);                                  \
    mine_.y = (a0.y + a1.y) + (a2.y + a3.y);                                  \
    if (act) *(float2*)&pex[w][pr_][2 * l] = mine_;                           \
    asm volatile("s_waitcnt lgkmcnt(0)" ::: "memory");                        \
    __builtin_amdgcn_s_barrier();                                             \
    const float2 o0_ = *(const float2*)&pex[0][pr_][2 * lc];                  \
    const float2 o1_ = *(const float2*)&pex[1][pr_][2 * lc];                  \
    const float2 o2_ = *(const float2*)&pex[2][pr_][2 * lc];                  \
    const float2 o3_ = *(const float2*)&pex[3][pr_][2 * lc];                  \
    const float qx_ = (o0_.x + o1_.x) + (o2_.x + o3_.x);                      \
    const float qy_ = (o0_.y + o1_.y) + (o2_.y + o3_.y);                      \
    if (BIT_) { px = qx_ * scx_; py = qy_ * scy_; }                           \
    if (REN_) {                                                               \
        float r_ = px + py;                                                   \
        _Pragma("unroll")                                                     \
        for (int o_ = 32; o_; o_ >>= 1) r_ += __shfl_xor(r_, o_);             \
        const float inv_ = 1.0f / r_;                                         \
        px *= inv_; py *= inv_;                                               \
        S += (double)__logf(r_);                                              \
    }                                                                         \
    if (l >= wlo && l < whi)                                                  \
        *(float2*)&pb[w][pr_ ^ 1][2 * l - 24 * w] = make_float2(px, py);      \
} while (0)

__global__ __launch_bounds__(256, 2)
void crf_forward(const float* __restrict__ emissions,
                 const unsigned* __restrict__ mbits,
                 const float* __restrict__ start_t,
                 const float* __restrict__ end_t,
                 const float* __restrict__ E,
                 const float* __restrict__ maxT,
                 float* __restrict__ log_den) {
    const int b = blockIdx.x;
    const int w = threadIdx.x >> 6;       // wave 0..3: owns i-rows 24w..24w+23
    const int l = threadIdx.x & 63;       // lane: owns output pair (2l, 2l+1)
    const bool act = (l < 48);
    const int lc = act ? l : 47;
    const int s0 = 2 * lc;
    const int wlo = 12 * w, whi = 12 * w + 12;  // lanes writing own p-quarter

    __shared__ __align__(16) float pb[4][2][24];   // [wave][parity][i-local]
    __shared__ __align__(16) float pex[4][2][CC];  // partial exchange

    // E rows (24w + i) at columns (s0, s0+1) -> 24 float2 = 48 VGPRs
    float2 ep2[24];
#pragma unroll
    for (int i = 0; i < 24; ++i)
        ep2[i] = *(const float2*)(E + (size_t)(24 * w + i) * CC + s0);

    const float* ep = emissions + (size_t)b * TT * CC + s0;
    const float mTx = act ? maxT[s0]     : -INFINITY;
    const float mTy = act ? maxT[s0 + 1] : -INFINITY;

    // init t=0: p = exp(start + em0), replicated in all 4 waves
    float px = 0.f, py = 0.f;
    {
        const float2 e0 = *(const float2*)ep;
        if (act) {
            px = __expf(start_t[s0]     + e0.x);
            py = __expf(start_t[s0 + 1] + e0.y);
        }
    }
    double S = 0.0;
    if (l >= wlo && l < whi)
        *(float2*)&pb[w][1][2 * l - 24 * w] = make_float2(px, py);

    // emission prefetch slots: es[t&3] holds emission(t), t=1..4
    float2 es[4];
#pragma unroll
    for (int s = 1; s <= 4; ++s) es[s & 3] = *(const float2*)(ep + (size_t)s * CC);
    const float* pf = ep + (size_t)5 * CC;

    // head: t = 1..7
    const unsigned wb0 = mbits[b * 16];
#pragma unroll
    for (int k = 1; k < 8; ++k) {
        STEP(pf, k, (wb0 >> k) & 1u, 0);
        pf += CC;
    }
    // main: sb = 1..62 (t = 8*sb + k); renorm at k==0
    unsigned swc = wb0 >> 8;
    for (int sb = 1; sb < 63; ++sb) {
        const int sbn = sb + 1;
        const unsigned swn = mbits[b * 16 + (sbn >> 2)] >> ((sbn & 3) * 8);
#pragma unroll
        for (int k = 0; k < 8; ++k) {
            STEP(pf, k, (swc >> k) & 1u, k == 0);
            pf += CC;
        }
        swc = swn;
    }
    // tail: t = 504..511, prefetch clamped to t=511
#pragma unroll
    for (int k = 0; k < 8; ++k) {
        const int t_ = 504 + k;
        const int tn_ = (t_ + 4 <= TT - 1) ? (t_ + 4) : (TT - 1);
        STEP(ep + (size_t)tn_ * CC, k, (swc >> k) & 1u, k == 0);
    }

    // final: log_den = S + log(sum_j p[j] * exp(end[j]))  (replicated; wave 0 stores)
    float fr = act ? (px * __expf(end_t[s0]) + py * __expf(end_t[s0 + 1])) : 0.f;
#pragma unroll
    for (int off = 32; off; off >>= 1) fr += __shfl_xor(fr, off);
    if (threadIdx.x == 0) log_den[b] = (float)(S + (double)__logf(fr));
}

// ---------------------------------------------------------------------------
// Kernel 2: joint likelihood (numerator) — one block per batch.
// ---------------------------------------------------------------------------
__global__ __launch_bounds__(256) void crf_joint(const float* __restrict__ emissions,
                                                 const int* __restrict__ tags,
                                                 const int* __restrict__ mask,
                                                 const float* __restrict__ trans,
                                                 const float* __restrict__ start_t,
                                                 const float* __restrict__ end_t,
                                                 float* __restrict__ log_num) {
    const int b = blockIdx.x;
    const int tid = threadIdx.x;
    float s = 0.f;
    int mcount = 0;
    for (int t = tid; t < TT; t += 256) {
        int tg = tags[b * TT + t];
        float em = emissions[((size_t)b * TT + t) * CC + tg];
        int mk = mask[b * TT + t];
        mcount += mk;
        if (t == 0) {
            s += start_t[tg] + em;  // t=0 term unmasked in reference
        } else {
            int tp = tags[b * TT + t - 1];
            s += mk ? (trans[tp * CC + tg] + em) : 0.f;
        }
    }
    __shared__ float sred[4];
    __shared__ int mred[4];
#pragma unroll
    for (int off = 32; off; off >>= 1) {
        s += __shfl_xor(s, off);
        mcount += __shfl_xor(mcount, off);
    }
    if ((tid & 63) == 0) { sred[tid >> 6] = s; mred[tid >> 6] = mcount; }
    __syncthreads();
    if (tid == 0) {
        float tot = (sred[0] + sred[1]) + (sred[2] + sred[3]);
        int mt = (mred[0] + mred[1]) + (mred[2] + mred[3]);
        int last_tag = tags[b * TT + (mt - 1)];
        log_num[b] = tot + end_t[last_tag];
    }
}

// ---------------------------------------------------------------------------
// Kernel 3: final mean(log_den - log_num)
// ---------------------------------------------------------------------------
__global__ __launch_bounds__(512) void crf_final(const float* __restrict__ log_den,
                                                 const float* __restrict__ log_num,
                                                 float* __restrict__ out) {
    const int tid = threadIdx.x;
    float d = log_den[tid] - log_num[tid];
#pragma unroll
    for (int off = 32; off; off >>= 1) d += __shfl_xor(d, off);
    __shared__ float sred[8];
    if ((tid & 63) == 0) sred[tid >> 6] = d;
    __syncthreads();
    if (tid == 0) {
        float tot = 0.f;
        for (int w = 0; w < 8; ++w) tot += sred[w];
        out[0] = tot / (float)BB;
    }
}

extern "C" void kernel_launch(void* const* d_in, const int* in_sizes, int n_in,
                              void* d_out, int out_size, void* d_ws, size_t ws_size,
                              hipStream_t stream) {
    const float* emissions = (const float*)d_in[0];
    const int*   tags      = (const int*)d_in[1];
    const int*   mask      = (const int*)d_in[2];
    const float* trans     = (const float*)d_in[3];
    const float* start_t   = (const float*)d_in[4];
    const float* end_t     = (const float*)d_in[5];
    float* out = (float*)d_out;

    float*    ws      = (float*)d_ws;
    float*    E       = ws;               // 9216 floats
    float*    maxT    = ws + 9216;        // 96
    float*    log_den = ws + 9312;        // 512
    float*    log_num = ws + 9824;        // 512
    unsigned* mbits   = (unsigned*)(ws + 10336);  // 512*16 u32

    crf_prep<<<1, 128, 0, stream>>>(trans, E, maxT);
    pack_mask<<<BB, 64, 0, stream>>>(mask, mbits);
    crf_forward<<<BB, 256, 0, stream>>>(emissions, mbits, start_t, end_t, E, maxT, log_den);
    crf_joint<<<BB, 256, 0, stream>>>(emissions, tags, mask, trans, start_t, end_t, log_num);
    crf_final<<<1, 512, 0, stream>>>(log_den, log_num, out);
}